// Round 5
// baseline (6390.834 us; speedup 1.0000x reference)
//
#include <hip/hip_runtime.h>
#include <math.h>

#define HH 128
#define WW 128
#define NPIX 16384
#define CIN 3
#define DD 32
#define QQ 128
#define MM 16
#define NBATCH 2
#define EPSF 1e-8f
#define NBLK 512

// ---------------- conv1: 3x3, 3->32, relu, zero-pad SAME ----------------
__global__ __launch_bounds__(256) void conv1_kernel(
    const float* __restrict__ x, const float* __restrict__ w1,
    const float* __restrict__ b1, float* __restrict__ out)
{
    __shared__ float wlds[9 * CIN * DD];
    int t = threadIdx.x;
    for (int idx = t; idx < 9 * CIN * DD / 4; idx += 256)
        ((float4*)wlds)[idx] = ((const float4*)w1)[idx];
    __syncthreads();

    int ocq = t & 3;
    int pl  = t >> 2;
    int blk = blockIdx.x;                   // 512
    int b   = blk >> 8;
    int pix = (blk & 255) * 64 + pl;
    int i = pix >> 7, j = pix & 127;
    int ocb = ocq << 3;

    float4 acc0 = *(const float4*)(b1 + ocb);
    float4 acc1 = *(const float4*)(b1 + ocb + 4);
    #pragma unroll
    for (int dy = 0; dy < 3; dy++) {
        int ii = i + dy - 1;
        if (ii < 0 || ii >= HH) continue;
        #pragma unroll
        for (int dx = 0; dx < 3; dx++) {
            int jj = j + dx - 1;
            if (jj < 0 || jj >= WW) continue;
            const float* fr = x + ((size_t)((b << 14) + ii * WW + jj)) * CIN;
            float in0 = fr[0], in1 = fr[1], in2 = fr[2];
            const float* wp = wlds + (size_t)((dy * 3 + dx) * CIN) * DD + ocb;
            #pragma unroll
            for (int ic = 0; ic < 3; ic++) {
                float inv = (ic == 0) ? in0 : (ic == 1) ? in1 : in2;
                float4 w0 = *(const float4*)(wp + ic * DD);
                float4 w1v = *(const float4*)(wp + ic * DD + 4);
                acc0.x += inv * w0.x;  acc0.y += inv * w0.y;
                acc0.z += inv * w0.z;  acc0.w += inv * w0.w;
                acc1.x += inv * w1v.x; acc1.y += inv * w1v.y;
                acc1.z += inv * w1v.z; acc1.w += inv * w1v.w;
            }
        }
    }
    float* op = out + (((size_t)(b << 14) + pix) << 5) + ocb;
    float4 r0 = {fmaxf(acc0.x, 0.f), fmaxf(acc0.y, 0.f), fmaxf(acc0.z, 0.f), fmaxf(acc0.w, 0.f)};
    float4 r1 = {fmaxf(acc1.x, 0.f), fmaxf(acc1.y, 0.f), fmaxf(acc1.z, 0.f), fmaxf(acc1.w, 0.f)};
    *(float4*)op = r0;
    *(float4*)(op + 4) = r1;
}

// ---------------- conv2: 3x3, 32->32, relu ----------------
__global__ __launch_bounds__(256) void conv2_kernel(
    const float* __restrict__ fin, const float* __restrict__ w2,
    const float* __restrict__ b2, float* __restrict__ out)
{
    __shared__ float wlds[9 * DD * DD];    // 36.9 KB
    int t = threadIdx.x;
    for (int idx = t; idx < 9 * DD * DD / 4; idx += 256)
        ((float4*)wlds)[idx] = ((const float4*)w2)[idx];
    __syncthreads();

    int ocq = t & 3;
    int pl  = t >> 2;
    int blk = blockIdx.x;                   // 512
    int b   = blk >> 8;
    int pix = (blk & 255) * 64 + pl;
    int i = pix >> 7, j = pix & 127;
    int ocb = ocq << 3;

    float4 acc0 = *(const float4*)(b2 + ocb);
    float4 acc1 = *(const float4*)(b2 + ocb + 4);
    #pragma unroll
    for (int dy = 0; dy < 3; dy++) {
        int ii = i + dy - 1;
        if (ii < 0 || ii >= HH) continue;
        #pragma unroll
        for (int dx = 0; dx < 3; dx++) {
            int jj = j + dx - 1;
            if (jj < 0 || jj >= WW) continue;
            const float* fr = fin + (((size_t)(b << 14) + ii * WW + jj)) * DD;
            float iv[DD];
            #pragma unroll
            for (int c = 0; c < DD / 4; c++)
                ((float4*)iv)[c] = *(const float4*)(fr + c * 4);
            const float* wp = wlds + (size_t)((dy * 3 + dx) * DD) * DD + ocb;
            #pragma unroll
            for (int ic = 0; ic < DD; ic++) {
                float inv = iv[ic];
                float4 w0 = *(const float4*)(wp + ic * DD);
                float4 w1v = *(const float4*)(wp + ic * DD + 4);
                acc0.x += inv * w0.x;  acc0.y += inv * w0.y;
                acc0.z += inv * w0.z;  acc0.w += inv * w0.w;
                acc1.x += inv * w1v.x; acc1.y += inv * w1v.y;
                acc1.z += inv * w1v.z; acc1.w += inv * w1v.w;
            }
        }
    }
    float* op = out + (((size_t)(b << 14) + pix) << 5) + ocb;
    float4 r0 = {fmaxf(acc0.x, 0.f), fmaxf(acc0.y, 0.f), fmaxf(acc0.z, 0.f), fmaxf(acc0.w, 0.f)};
    float4 r1 = {fmaxf(acc1.x, 0.f), fmaxf(acc1.y, 0.f), fmaxf(acc1.z, 0.f), fmaxf(acc1.w, 0.f)};
    *(float4*)op = r0;
    *(float4*)(op + 4) = r1;
}

// ---------------- k/q 1x1 projections + row norms ----------------
__global__ __launch_bounds__(256) void kq_kernel(
    const float* __restrict__ fin, const float* __restrict__ wk,
    const float* __restrict__ bk, const float* __restrict__ wq,
    float* __restrict__ ksb, float* __restrict__ qsb,
    float* __restrict__ knorm, float* __restrict__ qnorm)
{
    int g  = blockIdx.x * 256 + threadIdx.x;  // B*N*32
    int oc = g & 31;
    int bp = g >> 5;
    const float* fr = fin + (size_t)bp * DD;
    float ak = bk[oc], aq = 0.0f;
    #pragma unroll
    for (int ic = 0; ic < DD; ic += 4) {
        float4 fv = *(const float4*)(fr + ic);
        ak += fv.x * wk[(ic + 0) * DD + oc];
        ak += fv.y * wk[(ic + 1) * DD + oc];
        ak += fv.z * wk[(ic + 2) * DD + oc];
        ak += fv.w * wk[(ic + 3) * DD + oc];
        aq += fv.x * wq[(ic + 0) * DD + oc];
        aq += fv.y * wq[(ic + 1) * DD + oc];
        aq += fv.z * wq[(ic + 2) * DD + oc];
        aq += fv.w * wq[(ic + 3) * DD + oc];
    }
    ksb[g] = ak;
    qsb[g] = aq;
    float ssk = ak * ak, ssq = aq * aq;
    #pragma unroll
    for (int m = 1; m < 32; m <<= 1) {
        ssk += __shfl_xor(ssk, m, 64);
        ssq += __shfl_xor(ssq, m, 64);
    }
    if (oc == 0) {
        knorm[bp] = sqrtf(ssk);
        qnorm[bp] = sqrtf(ssq);
    }
}

// ---------------- edge scores: LDS-tiled exp(cosine) + per-batch sums ----
__global__ __launch_bounds__(256) void edge_kernel(
    const float* __restrict__ ksb, const float* __restrict__ qsb,
    const float* __restrict__ knorm, const float* __restrict__ qnorm,
    float* __restrict__ wT, float* __restrict__ sums)
{
    __shared__ float kt[144][36];
    __shared__ float qt[64][36];
    __shared__ float kn[144];
    __shared__ float qn[64];
    __shared__ float red[4];
    const int t   = threadIdx.x;
    const int blk = blockIdx.x;     // 512
    const int b   = blk >> 8;
    const int tl  = blk & 255;
    const int ti0 = (tl >> 4) << 3, tj0 = (tl & 15) << 3;
    const float* kb = ksb + ((size_t)b << 19);
    const float* qb = qsb + ((size_t)b << 19);

    for (int idx = t; idx < 144 * 8; idx += 256) {
        int row = idx >> 3, quad = idx & 7;
        int ar = row / 12, ac = row - ar * 12;
        int gi = min(max(ti0 + ar - 2, 0), HH - 1);
        int gj = min(max(tj0 + ac - 2, 0), WW - 1);
        *(float4*)&kt[row][quad << 2] =
            *(const float4*)(kb + ((size_t)(gi * WW + gj) << 5) + (quad << 2));
    }
    for (int idx = t; idx < 64 * 8; idx += 256) {
        int row = idx >> 3, quad = idx & 7;
        int gp = (ti0 + (row >> 3)) * WW + tj0 + (row & 7);
        *(float4*)&qt[row][quad << 2] =
            *(const float4*)(qb + ((size_t)gp << 5) + (quad << 2));
    }
    if (t < 144) {
        int ar = t / 12, ac = t - ar * 12;
        int gi = min(max(ti0 + ar - 2, 0), HH - 1);
        int gj = min(max(tj0 + ac - 2, 0), WW - 1);
        kn[t] = knorm[(b << 14) + gi * WW + gj];
    } else if (t < 208) {
        int r2 = t - 144;
        int gp = (ti0 + (r2 >> 3)) * WW + tj0 + (r2 & 7);
        qn[r2] = qnorm[(b << 14) + gp];
    }
    __syncthreads();

    const int nl = t >> 2, s = t & 3;
    const int p = nl >> 3, q = nl & 7;
    float4 qv[8];
    #pragma unroll
    for (int c = 0; c < 8; c++) qv[c] = *(const float4*)&qt[nl][c << 2];
    const float qnv = qn[nl];
    const int gp = (ti0 + p) * WW + tj0 + q;
    float* wrow = wT + (((size_t)(b << 14) + gp) << 5);
    float lsum = 0.0f;
    for (int o = s; o < 25; o += 4) {
        int di = o / 5, dj = o - di * 5;
        int krow = (p + di) * 12 + (q + dj);
        const float* kr = &kt[krow][0];
        float dot = 0.0f;
        #pragma unroll
        for (int c = 0; c < 8; c++) {
            float4 kv = *(const float4*)(kr + (c << 2));
            dot += qv[c].x * kv.x + qv[c].y * kv.y + qv[c].z * kv.z + qv[c].w * kv.w;
        }
        float den = fmaxf(qnv * kn[krow], EPSF);
        float es = expf(dot / den);
        wrow[o] = es;
        lsum += es;
    }
    #pragma unroll
    for (int mm = 1; mm < 64; mm <<= 1) lsum += __shfl_xor(lsum, mm, 64);
    if ((t & 63) == 0) red[t >> 6] = lsum;
    __syncthreads();
    if (t == 0) atomicAdd(&sums[b], red[0] + red[1] + red[2] + red[3]);
}

// ---------------- persistent propagation (all 32 iters), plain launch ----
// 512 blocks x 256 thr. Co-residency BY CONSTRUCTION: __launch_bounds__(256,2)
// caps VGPR<=256 (2 waves/SIMD) and static LDS 57KB => exactly 2 blocks/CU
// x 256 CUs = 512. Grid barrier = monotone device-scope atomic counter with
// __threadfence() release BEFORE and acquire AFTER (cross-XCD L2 wb + inv).
// Own-tile h in registers; only 48 boundary px/tile published per iter;
// mask head fused (needs no barrier after last iter).
__global__ __launch_bounds__(256, 2) void prop_persist(
    const float* __restrict__ hinit, float* __restrict__ hA,
    float* __restrict__ hB, const float* __restrict__ wT,
    const float* __restrict__ sums, float* __restrict__ out,
    const float* __restrict__ wm, int* __restrict__ bar)
{
    __shared__ float4 tile_s[144 * 17];   // 39.2 KB
    __shared__ float wts[64][36];         // 9.2 KB pre-scaled softmax weights
    __shared__ float wls[QQ * 17];        // 8.7 KB w_mask padded

    const int t = threadIdx.x;
    const int x = blockIdx.x & 7;          // XCD slab swizzle
    const int r = blockIdx.x >> 3;
    const int g_tr = (x << 2) + (r >> 4);  // global tile-row 0..31
    const int b   = g_tr >> 4;
    const int ti0 = (g_tr & 15) << 3;
    const int tj0 = (r & 15) << 3;

    // ---- one-time staging: wts (scaled) + w_mask ----
    {
        float invs = 1.0f / sums[b];
        const float* wbase = wT + (((size_t)(b << 14) + ti0 * WW + tj0) << 5);
        for (int idx = t; idx < 512; idx += 256) {
            int p = idx >> 6, rest = idx & 63;
            float4 v = *(const float4*)(wbase + (((size_t)p * WW) << 5) + (rest << 2));
            int nl = (p << 3) + (rest >> 3);
            int c4 = (rest & 7) << 2;
            float4 sv = {v.x * invs, v.y * invs, v.z * invs, v.w * invs};
            *(float4*)&wts[nl][c4] = sv;
        }
        for (int idx = t; idx < QQ * MM; idx += 256) {
            int c = idx >> 4, m = idx & 15;
            wls[c * 17 + m] = wm[idx];
        }
    }

    const int s  = t & 15;
    const int g  = t >> 4;
    const int q  = g & 7;
    const int rb = g >> 3;

    // own-tile h in registers: hcur[slab][k] = node (row rb*4+k, col q)
    float4 hcur[2][4];
    {
        const float* hb0 = hinit + ((size_t)b << 21);
        #pragma unroll
        for (int sl = 0; sl < 2; sl++)
            #pragma unroll
            for (int k = 0; k < 4; k++) {
                int gp = (ti0 + (rb << 2) + k) * WW + (tj0 + q);
                hcur[sl][k] = *(const float4*)(hb0 + ((size_t)gp << 7) + (sl << 6) + (s << 2));
            }
    }

    for (int it = 0; it < 32; it++) {
        const float* hsrc = (it == 0) ? hinit : (((it - 1) & 1) ? hB : hA);
        const float* hb   = hsrc + ((size_t)b << 21);

        float4 acc[2][4];
        #pragma unroll
        for (int sl = 0; sl < 2; sl++)
            #pragma unroll
            for (int k = 0; k < 4; k++) acc[sl][k] = {0.f, 0.f, 0.f, 0.f};

        #pragma unroll
        for (int sl = 0; sl < 2; sl++) {
            __syncthreads();   // WAR: prior tile_s reads done (also wts @ it0)
            // own tile from registers
            #pragma unroll
            for (int k = 0; k < 4; k++)
                tile_s[((2 + (rb << 2) + k) * 12 + (2 + q)) * 17 + s] = hcur[sl][k];
            // 80 halo px from global: 1280 float4 tasks / 256 thr = 5 each
            #pragma unroll
            for (int j = 0; j < 5; j++) {
                int task = (j << 8) + t;
                int hp = task >> 4, slot = task & 15;
                int ar, ac;
                if (hp < 48) {
                    int rr = hp / 12;
                    ar = (rr & 1) + ((rr >> 1) * 10);       // rows 0,1,10,11
                    ac = hp - rr * 12;
                } else {
                    int h2 = hp - 48;
                    ar = 2 + (h2 >> 2);
                    int acl = h2 & 3;
                    ac = acl + ((acl >> 1) * 8);            // cols 0,1,10,11
                }
                int gi = min(max(ti0 + ar - 2, 0), HH - 1);
                int gj = min(max(tj0 + ac - 2, 0), WW - 1);
                tile_s[(ar * 12 + ac) * 17 + slot] =
                    *(const float4*)(hb + ((size_t)(gi * WW + gj) << 7) + (sl << 6) + (slot << 2));
            }
            __syncthreads();

            #pragma unroll
            for (int dj = 0; dj < 5; dj++) {
                int ccol = q + dj;
                #pragma unroll
                for (int a = 0; a < 8; a++) {
                    int trow = (rb << 2) + a;
                    float4 v = tile_s[(trow * 12 + ccol) * 17 + s];
                    #pragma unroll
                    for (int k = 0; k < 4; k++) {
                        if (k < a - 4 || k > a) continue;   // compile-time pruned
                        int nl = (((rb << 2) + k) << 3) + q;
                        float w = wts[nl][(a - k) * 5 + dj];
                        acc[sl][k].x += w * v.x;
                        acc[sl][k].y += w * v.y;
                        acc[sl][k].z += w * v.z;
                        acc[sl][k].w += w * v.w;
                    }
                }
            }
        }

        // norm + update registers; publish boundary px only (if more iters)
        float* hw = (it & 1) ? hB : hA;
        #pragma unroll
        for (int k = 0; k < 4; k++) {
            float ss = acc[0][k].x * acc[0][k].x + acc[0][k].y * acc[0][k].y +
                       acc[0][k].z * acc[0][k].z + acc[0][k].w * acc[0][k].w +
                       acc[1][k].x * acc[1][k].x + acc[1][k].y * acc[1][k].y +
                       acc[1][k].z * acc[1][k].z + acc[1][k].w * acc[1][k].w;
            ss += __shfl_xor(ss, 1, 64);
            ss += __shfl_xor(ss, 2, 64);
            ss += __shfl_xor(ss, 4, 64);
            ss += __shfl_xor(ss, 8, 64);
            float rs = 1.0f / (sqrtf(ss) + EPSF);
            #pragma unroll
            for (int sl = 0; sl < 2; sl++) {
                hcur[sl][k].x = acc[sl][k].x * rs;
                hcur[sl][k].y = acc[sl][k].y * rs;
                hcur[sl][k].z = acc[sl][k].z * rs;
                hcur[sl][k].w = acc[sl][k].w * rs;
            }
            if (it < 31) {
                int p = (rb << 2) + k;
                if ((q < 2) | (q > 5) | (p < 2) | (p > 5)) {   // boundary px
                    int gp = (ti0 + p) * WW + (tj0 + q);
                    float* orow = hw + (((size_t)(b << 14) + gp) << 7);
                    *(float4*)(orow + (s << 2))      = hcur[0][k];
                    *(float4*)(orow + 64 + (s << 2)) = hcur[1][k];
                }
            }
        }

        // ---- grid barrier: release-fence, arrive, spin, acquire-fence ----
        if (it < 31) {
            __threadfence();            // drain stores + L2 writeback (agent)
            __syncthreads();            // all threads' fences done
            if (t == 0) {
                __hip_atomic_fetch_add(bar, 1, __ATOMIC_RELEASE,
                                       __HIP_MEMORY_SCOPE_AGENT);
                int target = (it + 1) * NBLK;
                long guard = 0;
                while (__hip_atomic_load(bar, __ATOMIC_ACQUIRE,
                                         __HIP_MEMORY_SCOPE_AGENT) < target) {
                    __builtin_amdgcn_s_sleep(2);
                    if (++guard > (200L << 20)) break;   // never hang
                }
            }
            __syncthreads();
            __threadfence();            // invalidate stale L1/L2 (agent)
        }
    }

    // ---- fused mask head: logits from register h, softmax(16), write ----
    float pm[4][16];
    #pragma unroll
    for (int k = 0; k < 4; k++)
        #pragma unroll
        for (int m = 0; m < 16; m++) pm[k][m] = 0.0f;
    #pragma unroll
    for (int k = 0; k < 4; k++) {
        #pragma unroll
        for (int j = 0; j < 4; j++) {
            float h0 = ((const float*)&hcur[0][k])[j];   // channel 4s+j
            float h1 = ((const float*)&hcur[1][k])[j];   // channel 64+4s+j
            const float* w0 = wls + ((4 * s + j) * 17);
            const float* w1 = wls + ((64 + 4 * s + j) * 17);
            #pragma unroll
            for (int m = 0; m < 16; m++)
                pm[k][m] += h0 * w0[m] + h1 * w1[m];
        }
    }
    #pragma unroll
    for (int k = 0; k < 4; k++)
        #pragma unroll
        for (int m = 0; m < 16; m++) {
            pm[k][m] += __shfl_xor(pm[k][m], 1, 64);
            pm[k][m] += __shfl_xor(pm[k][m], 2, 64);
            pm[k][m] += __shfl_xor(pm[k][m], 4, 64);
            pm[k][m] += __shfl_xor(pm[k][m], 8, 64);
        }
    __syncthreads();                      // tile_s reads done; reuse as maskbuf
    float* maskbuf = (float*)tile_s;      // [64 px][17]
    #pragma unroll
    for (int k = 0; k < 4; k++) {
        float mx = pm[k][0];
        #pragma unroll
        for (int m = 1; m < 16; m++) mx = fmaxf(mx, pm[k][m]);
        float sum = 0.0f;
        float es[16];
        #pragma unroll
        for (int m = 0; m < 16; m++) { es[m] = expf(pm[k][m] - mx); sum += es[m]; }
        float inv = 1.0f / sum;
        float val = 0.0f;
        #pragma unroll
        for (int m = 0; m < 16; m++) if (m == s) val = es[m];
        int nl = (((rb << 2) + k) << 3) + q;
        maskbuf[nl * 17 + s] = val * inv;
    }
    __syncthreads();
    {
        int m = t >> 4, grp = t & 15;
        #pragma unroll
        for (int e = 0; e < 4; e++) {
            int px = (grp << 2) + e;
            int p = px >> 3, qq = px & 7;
            out[(((size_t)((b << 4) + m)) << 14) + (ti0 + p) * WW + (tj0 + qq)] =
                maskbuf[px * 17 + m];
        }
    }
}

extern "C" void kernel_launch(void* const* d_in, const int* in_sizes, int n_in,
                              void* d_out, int out_size, void* d_ws, size_t ws_size,
                              hipStream_t stream)
{
    const float* x     = (const float*)d_in[0];
    // d_in[1] = edges (int32) -- unused: row/col are analytic
    const float* w1    = (const float*)d_in[2];
    const float* b1    = (const float*)d_in[3];
    const float* w2    = (const float*)d_in[4];
    const float* b2    = (const float*)d_in[5];
    const float* wk    = (const float*)d_in[6];
    const float* bk    = (const float*)d_in[7];
    const float* wq    = (const float*)d_in[8];
    const float* hinit = (const float*)d_in[9];
    const float* wm    = (const float*)d_in[10];
    float* out = (float*)d_out;

    char* ws = (char*)d_ws;
    size_t off = 0;
    auto alloc = [&](size_t bytes) -> void* {
        void* p = ws + off;
        off += (bytes + 255) & ~(size_t)255;
        return p;
    };
    float* feat1 = (float*)alloc((size_t)NBATCH * NPIX * DD * 4);
    float* feat2 = (float*)alloc((size_t)NBATCH * NPIX * DD * 4);
    float* ksb   = (float*)alloc((size_t)NBATCH * NPIX * DD * 4);
    float* qsb   = (float*)alloc((size_t)NBATCH * NPIX * DD * 4);
    float* knorm = (float*)alloc((size_t)NBATCH * NPIX * 4);
    float* qnorm = (float*)alloc((size_t)NBATCH * NPIX * 4);
    float* wT    = (float*)alloc((size_t)NBATCH * NPIX * 32 * 4);
    float* sums  = (float*)alloc(256);     // [0..1]=sums, +64B = barrier
    float* hA    = (float*)alloc((size_t)NBATCH * NPIX * QQ * 4);
    float* hB    = (float*)alloc((size_t)NBATCH * NPIX * QQ * 4);
    int*   bar   = (int*)((char*)sums + 64);

    hipMemsetAsync(sums, 0, 256, stream);   // zeroes sums + barrier counter

    conv1_kernel<<<512, 256, 0, stream>>>(x, w1, b1, feat1);
    conv2_kernel<<<512, 256, 0, stream>>>(feat1, w2, b2, feat2);
    kq_kernel<<<4096, 256, 0, stream>>>(feat2, wk, bk, wq, ksb, qsb, knorm, qnorm);
    edge_kernel<<<512, 256, 0, stream>>>(ksb, qsb, knorm, qnorm, wT, sums);
    prop_persist<<<NBLK, 256, 0, stream>>>(hinit, hA, hB, wT, sums, out, wm, bar);
}

// Round 6
// 826.703 us; speedup vs baseline: 7.7305x; 7.7305x over previous
//
#include <hip/hip_runtime.h>
#include <hip/hip_fp16.h>
#include <math.h>

#define HH 128
#define WW 128
#define NPIX 16384
#define CIN 3
#define DD 32
#define QQ 128
#define MM 16
#define NBATCH 2
#define EPSF 1e-8f

// ---------------- conv1: 3x3, 3->32, relu, zero-pad SAME ----------------
__global__ __launch_bounds__(256) void conv1_kernel(
    const float* __restrict__ x, const float* __restrict__ w1,
    const float* __restrict__ b1, float* __restrict__ out)
{
    __shared__ float wlds[9 * CIN * DD];
    int t = threadIdx.x;
    for (int idx = t; idx < 9 * CIN * DD / 4; idx += 256)
        ((float4*)wlds)[idx] = ((const float4*)w1)[idx];
    __syncthreads();

    int ocq = t & 3;
    int pl  = t >> 2;
    int blk = blockIdx.x;                   // 512
    int b   = blk >> 8;
    int pix = (blk & 255) * 64 + pl;
    int i = pix >> 7, j = pix & 127;
    int ocb = ocq << 3;

    float4 acc0 = *(const float4*)(b1 + ocb);
    float4 acc1 = *(const float4*)(b1 + ocb + 4);
    #pragma unroll
    for (int dy = 0; dy < 3; dy++) {
        int ii = i + dy - 1;
        if (ii < 0 || ii >= HH) continue;
        #pragma unroll
        for (int dx = 0; dx < 3; dx++) {
            int jj = j + dx - 1;
            if (jj < 0 || jj >= WW) continue;
            const float* fr = x + ((size_t)((b << 14) + ii * WW + jj)) * CIN;
            float in0 = fr[0], in1 = fr[1], in2 = fr[2];
            const float* wp = wlds + (size_t)((dy * 3 + dx) * CIN) * DD + ocb;
            #pragma unroll
            for (int ic = 0; ic < 3; ic++) {
                float inv = (ic == 0) ? in0 : (ic == 1) ? in1 : in2;
                float4 w0 = *(const float4*)(wp + ic * DD);
                float4 w1v = *(const float4*)(wp + ic * DD + 4);
                acc0.x += inv * w0.x;  acc0.y += inv * w0.y;
                acc0.z += inv * w0.z;  acc0.w += inv * w0.w;
                acc1.x += inv * w1v.x; acc1.y += inv * w1v.y;
                acc1.z += inv * w1v.z; acc1.w += inv * w1v.w;
            }
        }
    }
    float* op = out + (((size_t)(b << 14) + pix) << 5) + ocb;
    float4 r0 = {fmaxf(acc0.x, 0.f), fmaxf(acc0.y, 0.f), fmaxf(acc0.z, 0.f), fmaxf(acc0.w, 0.f)};
    float4 r1 = {fmaxf(acc1.x, 0.f), fmaxf(acc1.y, 0.f), fmaxf(acc1.z, 0.f), fmaxf(acc1.w, 0.f)};
    *(float4*)op = r0;
    *(float4*)(op + 4) = r1;
}

// ---------------- conv2: 3x3, 32->32, relu ----------------
__global__ __launch_bounds__(256) void conv2_kernel(
    const float* __restrict__ fin, const float* __restrict__ w2,
    const float* __restrict__ b2, float* __restrict__ out)
{
    __shared__ float wlds[9 * DD * DD];    // 36.9 KB
    int t = threadIdx.x;
    for (int idx = t; idx < 9 * DD * DD / 4; idx += 256)
        ((float4*)wlds)[idx] = ((const float4*)w2)[idx];
    __syncthreads();

    int ocq = t & 3;
    int pl  = t >> 2;
    int blk = blockIdx.x;                   // 512
    int b   = blk >> 8;
    int pix = (blk & 255) * 64 + pl;
    int i = pix >> 7, j = pix & 127;
    int ocb = ocq << 3;

    float4 acc0 = *(const float4*)(b2 + ocb);
    float4 acc1 = *(const float4*)(b2 + ocb + 4);
    #pragma unroll
    for (int dy = 0; dy < 3; dy++) {
        int ii = i + dy - 1;
        if (ii < 0 || ii >= HH) continue;
        #pragma unroll
        for (int dx = 0; dx < 3; dx++) {
            int jj = j + dx - 1;
            if (jj < 0 || jj >= WW) continue;
            const float* fr = fin + (((size_t)(b << 14) + ii * WW + jj)) * DD;
            float iv[DD];
            #pragma unroll
            for (int c = 0; c < DD / 4; c++)
                ((float4*)iv)[c] = *(const float4*)(fr + c * 4);
            const float* wp = wlds + (size_t)((dy * 3 + dx) * DD) * DD + ocb;
            #pragma unroll
            for (int ic = 0; ic < DD; ic++) {
                float inv = iv[ic];
                float4 w0 = *(const float4*)(wp + ic * DD);
                float4 w1v = *(const float4*)(wp + ic * DD + 4);
                acc0.x += inv * w0.x;  acc0.y += inv * w0.y;
                acc0.z += inv * w0.z;  acc0.w += inv * w0.w;
                acc1.x += inv * w1v.x; acc1.y += inv * w1v.y;
                acc1.z += inv * w1v.z; acc1.w += inv * w1v.w;
            }
        }
    }
    float* op = out + (((size_t)(b << 14) + pix) << 5) + ocb;
    float4 r0 = {fmaxf(acc0.x, 0.f), fmaxf(acc0.y, 0.f), fmaxf(acc0.z, 0.f), fmaxf(acc0.w, 0.f)};
    float4 r1 = {fmaxf(acc1.x, 0.f), fmaxf(acc1.y, 0.f), fmaxf(acc1.z, 0.f), fmaxf(acc1.w, 0.f)};
    *(float4*)op = r0;
    *(float4*)(op + 4) = r1;
}

// ---------------- k/q 1x1 projections + row norms ----------------
__global__ __launch_bounds__(256) void kq_kernel(
    const float* __restrict__ fin, const float* __restrict__ wk,
    const float* __restrict__ bk, const float* __restrict__ wq,
    float* __restrict__ ksb, float* __restrict__ qsb,
    float* __restrict__ knorm, float* __restrict__ qnorm)
{
    int g  = blockIdx.x * 256 + threadIdx.x;  // B*N*32
    int oc = g & 31;
    int bp = g >> 5;
    const float* fr = fin + (size_t)bp * DD;
    float ak = bk[oc], aq = 0.0f;
    #pragma unroll
    for (int ic = 0; ic < DD; ic += 4) {
        float4 fv = *(const float4*)(fr + ic);
        ak += fv.x * wk[(ic + 0) * DD + oc];
        ak += fv.y * wk[(ic + 1) * DD + oc];
        ak += fv.z * wk[(ic + 2) * DD + oc];
        ak += fv.w * wk[(ic + 3) * DD + oc];
        aq += fv.x * wq[(ic + 0) * DD + oc];
        aq += fv.y * wq[(ic + 1) * DD + oc];
        aq += fv.z * wq[(ic + 2) * DD + oc];
        aq += fv.w * wq[(ic + 3) * DD + oc];
    }
    ksb[g] = ak;
    qsb[g] = aq;
    float ssk = ak * ak, ssq = aq * aq;
    #pragma unroll
    for (int m = 1; m < 32; m <<= 1) {
        ssk += __shfl_xor(ssk, m, 64);
        ssq += __shfl_xor(ssq, m, 64);
    }
    if (oc == 0) {
        knorm[bp] = sqrtf(ssk);
        qnorm[bp] = sqrtf(ssq);
    }
}

// ---------------- edge scores: LDS-tiled exp(cosine) -> fp16 wT ----------
__global__ __launch_bounds__(256) void edge_kernel(
    const float* __restrict__ ksb, const float* __restrict__ qsb,
    const float* __restrict__ knorm, const float* __restrict__ qnorm,
    __half* __restrict__ wT, float* __restrict__ sums)
{
    __shared__ float kt[144][36];
    __shared__ float qt[64][36];
    __shared__ float kn[144];
    __shared__ float qn[64];
    __shared__ float red[4];
    const int t   = threadIdx.x;
    const int blk = blockIdx.x;     // 512
    const int b   = blk >> 8;
    const int tl  = blk & 255;
    const int ti0 = (tl >> 4) << 3, tj0 = (tl & 15) << 3;
    const float* kb = ksb + ((size_t)b << 19);
    const float* qb = qsb + ((size_t)b << 19);

    for (int idx = t; idx < 144 * 8; idx += 256) {
        int row = idx >> 3, quad = idx & 7;
        int ar = row / 12, ac = row - ar * 12;
        int gi = min(max(ti0 + ar - 2, 0), HH - 1);
        int gj = min(max(tj0 + ac - 2, 0), WW - 1);
        *(float4*)&kt[row][quad << 2] =
            *(const float4*)(kb + ((size_t)(gi * WW + gj) << 5) + (quad << 2));
    }
    for (int idx = t; idx < 64 * 8; idx += 256) {
        int row = idx >> 3, quad = idx & 7;
        int gp = (ti0 + (row >> 3)) * WW + tj0 + (row & 7);
        *(float4*)&qt[row][quad << 2] =
            *(const float4*)(qb + ((size_t)gp << 5) + (quad << 2));
    }
    if (t < 144) {
        int ar = t / 12, ac = t - ar * 12;
        int gi = min(max(ti0 + ar - 2, 0), HH - 1);
        int gj = min(max(tj0 + ac - 2, 0), WW - 1);
        kn[t] = knorm[(b << 14) + gi * WW + gj];
    } else if (t < 208) {
        int r2 = t - 144;
        int gp = (ti0 + (r2 >> 3)) * WW + tj0 + (r2 & 7);
        qn[r2] = qnorm[(b << 14) + gp];
    }
    __syncthreads();

    const int nl = t >> 2, s = t & 3;
    const int p = nl >> 3, q = nl & 7;
    float4 qv[8];
    #pragma unroll
    for (int c = 0; c < 8; c++) qv[c] = *(const float4*)&qt[nl][c << 2];
    const float qnv = qn[nl];
    const int gp = (ti0 + p) * WW + tj0 + q;
    __half* wrow = wT + (((size_t)(b << 14) + gp) << 5);
    float lsum = 0.0f;
    for (int o = s; o < 25; o += 4) {
        int di = o / 5, dj = o - di * 5;
        int krow = (p + di) * 12 + (q + dj);
        const float* kr = &kt[krow][0];
        float dot = 0.0f;
        #pragma unroll
        for (int c = 0; c < 8; c++) {
            float4 kv = *(const float4*)(kr + (c << 2));
            dot += qv[c].x * kv.x + qv[c].y * kv.y + qv[c].z * kv.z + qv[c].w * kv.w;
        }
        float den = fmaxf(qnv * kn[krow], EPSF);
        float es = expf(dot / den);     // cosine in [-1,1]: es in [0.37, 2.72]
        wrow[o] = __float2half(es);
        lsum += es;
    }
    #pragma unroll
    for (int mm = 1; mm < 64; mm <<= 1) lsum += __shfl_xor(lsum, mm, 64);
    if ((t & 63) == 0) red[t >> 6] = lsum;
    __syncthreads();
    if (t == 0) atomicAdd(&sums[b], red[0] + red[1] + red[2] + red[3]);
}

// ---------------- one propagation iteration (fp16 h, conflict-free LDS) --
// Block = 8x8 tile; 12x12 halo staged per 64-ch slab, CONVERTED TO FLOAT at
// stage time. tile_l row stride 65 floats (== 1 mod 32): compute reads are
// 4x ds_read_b32 with 2 lanes/bank (free). wts stride 33: broadcast (free).
// h stored fp16 globally (halves HBM traffic vs round-3 fp32).
#define TS 65
template<bool FIRST>
__global__ __launch_bounds__(256) void prop_it(
    const void* __restrict__ hsrc_, __half* __restrict__ hdst,
    const __half* __restrict__ wTh, const float* __restrict__ sums)
{
    __shared__ float tile_l[144 * TS];   // 37.4 KB
    __shared__ float wts_l[64 * 33];     // 8.4 KB
    const int t   = threadIdx.x;
    const int blk = blockIdx.x;          // 512
    const int b   = blk >> 8;
    const int tl  = blk & 255;
    const int ti0 = (tl >> 4) << 3, tj0 = (tl & 15) << 3;

    // ---- stage wts (softmax-scaled, half -> float) ----
    {
        float invs = 1.0f / sums[b];
        int node = t >> 2, chunk = t & 3;        // 8 halfs per thread
        int p = node >> 3, q = node & 7;
        int gp = (ti0 + p) * WW + tj0 + q;
        const __half* wrow = wTh + (((size_t)(b << 14) + gp) << 5) + (chunk << 3);
        uint4 raw = *(const uint4*)wrow;
        const __half2* hp = (const __half2*)&raw;
        int base = node * 33 + (chunk << 3);
        #pragma unroll
        for (int u = 0; u < 4; u++) {
            float2 f = __half22float2(hp[u]);
            wts_l[base + 2 * u]     = f.x * invs;
            wts_l[base + 2 * u + 1] = f.y * invs;
        }
    }

    const int s  = t & 15;
    const int q  = (t >> 4) & 7;
    const int rb = t >> 7;
    const int ch0 = s << 2;

    float4 acc[2][4];
    #pragma unroll
    for (int sl = 0; sl < 2; sl++)
        #pragma unroll
        for (int k = 0; k < 4; k++) acc[sl][k] = {0.f, 0.f, 0.f, 0.f};

    #pragma unroll
    for (int sl = 0; sl < 2; sl++) {
        __syncthreads();            // WAR on tile_l (and wts visibility @sl=0)
        // stage 144 px x 64 ch (as float): 1152 16B-source tasks
        #pragma unroll
        for (int j = 0; j < 5; j++) {
            int idx = (j << 8) + t;
            if (idx < 1152) {
                int pr = idx >> 3, chunk = idx & 7;
                int ar = pr / 12, ac = pr - ar * 12;
                int gi = min(max(ti0 + ar - 2, 0), HH - 1);
                int gj = min(max(tj0 + ac - 2, 0), WW - 1);
                float f[8];
                if (FIRST) {
                    const float* src = (const float*)hsrc_ +
                        (((size_t)(b << 14) + gi * WW + gj) << 7) + (sl << 6) + (chunk << 3);
                    float4 x0 = *(const float4*)src;
                    float4 x1 = *(const float4*)(src + 4);
                    f[0]=x0.x; f[1]=x0.y; f[2]=x0.z; f[3]=x0.w;
                    f[4]=x1.x; f[5]=x1.y; f[6]=x1.z; f[7]=x1.w;
                } else {
                    const __half* src = (const __half*)hsrc_ +
                        (((size_t)(b << 14) + gi * WW + gj) << 7) + (sl << 6) + (chunk << 3);
                    uint4 raw = *(const uint4*)src;
                    const __half2* hp = (const __half2*)&raw;
                    #pragma unroll
                    for (int u = 0; u < 4; u++) {
                        float2 ff = __half22float2(hp[u]);
                        f[2 * u] = ff.x; f[2 * u + 1] = ff.y;
                    }
                }
                int base = pr * TS + (chunk << 3);
                #pragma unroll
                for (int u = 0; u < 8; u++) tile_l[base + u] = f[u];  // b32s: 2-way free
            }
        }
        __syncthreads();

        // compute: register-blocked 4 nodes (k) per thread
        #pragma unroll
        for (int dj = 0; dj < 5; dj++) {
            int ccol = q + dj;
            #pragma unroll
            for (int a = 0; a < 8; a++) {
                int base = ((rb * 4 + a) * 12 + ccol) * TS + ch0;
                float v0 = tile_l[base], v1 = tile_l[base + 1];
                float v2 = tile_l[base + 2], v3 = tile_l[base + 3];
                #pragma unroll
                for (int k = 0; k < 4; k++) {
                    if (k < a - 4 || k > a) continue;   // compile-time pruned
                    float w = wts_l[((((rb << 2) + k) << 3) + q) * 33 + (a - k) * 5 + dj];
                    acc[sl][k].x += w * v0;
                    acc[sl][k].y += w * v1;
                    acc[sl][k].z += w * v2;
                    acc[sl][k].w += w * v3;
                }
            }
        }
    }

    // ---- norm (shuffle over 16 s-lanes) + fp16 write ----
    #pragma unroll
    for (int k = 0; k < 4; k++) {
        float ss = acc[0][k].x * acc[0][k].x + acc[0][k].y * acc[0][k].y +
                   acc[0][k].z * acc[0][k].z + acc[0][k].w * acc[0][k].w +
                   acc[1][k].x * acc[1][k].x + acc[1][k].y * acc[1][k].y +
                   acc[1][k].z * acc[1][k].z + acc[1][k].w * acc[1][k].w;
        ss += __shfl_xor(ss, 1, 64);
        ss += __shfl_xor(ss, 2, 64);
        ss += __shfl_xor(ss, 4, 64);
        ss += __shfl_xor(ss, 8, 64);
        float rs = 1.0f / (sqrtf(ss) + EPSF);
        int gp = (ti0 + (rb << 2) + k) * WW + (tj0 + q);
        __half* orow = hdst + (((size_t)(b << 14) + gp) << 7);
        #pragma unroll
        for (int sl = 0; sl < 2; sl++) {
            union { uint2 u; __half2 h[2]; } pk;
            pk.h[0] = __floats2half2_rn(acc[sl][k].x * rs, acc[sl][k].y * rs);
            pk.h[1] = __floats2half2_rn(acc[sl][k].z * rs, acc[sl][k].w * rs);
            *(uint2*)(orow + (sl << 6) + (s << 2)) = pk.u;
        }
    }
}

// ---------------- mask head: fp16 h @ w_mask, softmax(16), transpose -----
__global__ __launch_bounds__(256) void mask_kernel(
    const __half* __restrict__ h, const float* __restrict__ wm,
    float* __restrict__ out)
{
    __shared__ float wls[QQ * MM];      // 8 KB, [c][m]
    __shared__ float part[64][4][20];
    const int t = threadIdx.x;
    for (int idx = t; idx < QQ * MM / 4; idx += 256)
        ((float4*)wls)[idx] = ((const float4*)wm)[idx];
    const int blk = blockIdx.x;         // 512
    const int b   = blk >> 8;
    const int n0  = (blk & 255) << 6;
    const int px  = t >> 2, s = t & 3;  // slot s: ch 32s..32s+31
    const __half* hr = h + ((((size_t)(b << 14) + n0 + px)) << 7) + (s << 5);
    __syncthreads();

    float acc[MM];
    #pragma unroll
    for (int m = 0; m < MM; m++) acc[m] = 0.0f;
    #pragma unroll
    for (int chunk = 0; chunk < 4; chunk++) {
        uint4 raw = ((const uint4*)hr)[chunk];
        const __half2* hp = (const __half2*)&raw;
        #pragma unroll
        for (int u = 0; u < 4; u++) {
            float2 hv = __half22float2(hp[u]);
            int c = (s << 5) + (chunk << 3) + 2 * u;
            const float* w0 = wls + (size_t)c * MM;
            const float* w1 = w0 + MM;
            #pragma unroll
            for (int m = 0; m < MM; m++)
                acc[m] += hv.x * w0[m] + hv.y * w1[m];
        }
    }
    #pragma unroll
    for (int m = 0; m < MM; m += 4)
        *(float4*)&part[px][s][m] = *(float4*)&acc[m];
    __syncthreads();

    // thread (px,s) reduces m-quad s over the 4 slots
    float4 r = {0, 0, 0, 0};
    #pragma unroll
    for (int ss = 0; ss < 4; ss++) {
        float4 v = *(const float4*)&part[px][ss][s << 2];
        r.x += v.x; r.y += v.y; r.z += v.z; r.w += v.w;
    }
    float mx = fmaxf(fmaxf(r.x, r.y), fmaxf(r.z, r.w));
    mx = fmaxf(mx, __shfl_xor(mx, 1, 64));
    mx = fmaxf(mx, __shfl_xor(mx, 2, 64));
    float4 e = {expf(r.x - mx), expf(r.y - mx), expf(r.z - mx), expf(r.w - mx)};
    float ls = e.x + e.y + e.z + e.w;
    ls += __shfl_xor(ls, 1, 64);
    ls += __shfl_xor(ls, 2, 64);
    float inv = 1.0f / ls;
    float* ob = out + (((size_t)((b << 4) + (s << 2))) << 14) + n0 + px;
    ob[0]             = e.x * inv;
    ob[1 << 14]       = e.y * inv;
    ob[2 << 14]       = e.z * inv;
    ob[3 * (1 << 14)] = e.w * inv;
}

extern "C" void kernel_launch(void* const* d_in, const int* in_sizes, int n_in,
                              void* d_out, int out_size, void* d_ws, size_t ws_size,
                              hipStream_t stream)
{
    const float* x     = (const float*)d_in[0];
    // d_in[1] = edges (int32) -- unused: row/col are analytic
    const float* w1    = (const float*)d_in[2];
    const float* b1    = (const float*)d_in[3];
    const float* w2    = (const float*)d_in[4];
    const float* b2    = (const float*)d_in[5];
    const float* wk    = (const float*)d_in[6];
    const float* bk    = (const float*)d_in[7];
    const float* wq    = (const float*)d_in[8];
    const float* hinit = (const float*)d_in[9];
    const float* wm    = (const float*)d_in[10];
    float* out = (float*)d_out;

    char* ws = (char*)d_ws;
    size_t off = 0;
    auto alloc = [&](size_t bytes) -> void* {
        void* p = ws + off;
        off += (bytes + 255) & ~(size_t)255;
        return p;
    };
    float*  feat1 = (float*)alloc((size_t)NBATCH * NPIX * DD * 4);
    float*  feat2 = (float*)alloc((size_t)NBATCH * NPIX * DD * 4);
    float*  ksb   = (float*)alloc((size_t)NBATCH * NPIX * DD * 4);
    float*  qsb   = (float*)alloc((size_t)NBATCH * NPIX * DD * 4);
    float*  knorm = (float*)alloc((size_t)NBATCH * NPIX * 4);
    float*  qnorm = (float*)alloc((size_t)NBATCH * NPIX * 4);
    __half* wTh   = (__half*)alloc((size_t)NBATCH * NPIX * 32 * 2);
    float*  sums  = (float*)alloc(256);
    __half* hA    = (__half*)alloc((size_t)NBATCH * NPIX * QQ * 2);
    __half* hB    = (__half*)alloc((size_t)NBATCH * NPIX * QQ * 2);

    hipMemsetAsync(sums, 0, 2 * sizeof(float), stream);

    conv1_kernel<<<512, 256, 0, stream>>>(x, w1, b1, feat1);
    conv2_kernel<<<512, 256, 0, stream>>>(feat1, w2, b2, feat2);
    kq_kernel<<<4096, 256, 0, stream>>>(feat2, wk, bk, wq, ksb, qsb, knorm, qnorm);
    edge_kernel<<<512, 256, 0, stream>>>(ksb, qsb, knorm, qnorm, wTh, sums);

    prop_it<true><<<512, 256, 0, stream>>>((const void*)hinit, hA, wTh, sums);
    const __half* src = hA;
    __half* dst;
    for (int it = 1; it < 32; it++) {
        dst = (it & 1) ? hB : hA;
        prop_it<false><<<512, 256, 0, stream>>>((const void*)src, dst, wTh, sums);
        src = dst;
    }
    mask_kernel<<<512, 256, 0, stream>>>(src, wm, out);
}

// Round 7
// 697.541 us; speedup vs baseline: 9.1619x; 1.1852x over previous
//
#include <hip/hip_runtime.h>
#include <hip/hip_fp16.h>
#include <math.h>

#define HH 128
#define WW 128
#define NPIX 16384
#define CIN 3
#define DD 32
#define QQ 128
#define MM 16
#define NBATCH 2
#define EPSF 1e-8f

// ---------------- conv1: 3x3, 3->32, relu, zero-pad SAME ----------------
__global__ __launch_bounds__(256) void conv1_kernel(
    const float* __restrict__ x, const float* __restrict__ w1,
    const float* __restrict__ b1, float* __restrict__ out)
{
    __shared__ float wlds[9 * CIN * DD];
    int t = threadIdx.x;
    for (int idx = t; idx < 9 * CIN * DD / 4; idx += 256)
        ((float4*)wlds)[idx] = ((const float4*)w1)[idx];
    __syncthreads();

    int ocq = t & 3;
    int pl  = t >> 2;
    int blk = blockIdx.x;                   // 512
    int b   = blk >> 8;
    int pix = (blk & 255) * 64 + pl;
    int i = pix >> 7, j = pix & 127;
    int ocb = ocq << 3;

    float4 acc0 = *(const float4*)(b1 + ocb);
    float4 acc1 = *(const float4*)(b1 + ocb + 4);
    #pragma unroll
    for (int dy = 0; dy < 3; dy++) {
        int ii = i + dy - 1;
        if (ii < 0 || ii >= HH) continue;
        #pragma unroll
        for (int dx = 0; dx < 3; dx++) {
            int jj = j + dx - 1;
            if (jj < 0 || jj >= WW) continue;
            const float* fr = x + ((size_t)((b << 14) + ii * WW + jj)) * CIN;
            float in0 = fr[0], in1 = fr[1], in2 = fr[2];
            const float* wp = wlds + (size_t)((dy * 3 + dx) * CIN) * DD + ocb;
            #pragma unroll
            for (int ic = 0; ic < 3; ic++) {
                float inv = (ic == 0) ? in0 : (ic == 1) ? in1 : in2;
                float4 w0 = *(const float4*)(wp + ic * DD);
                float4 w1v = *(const float4*)(wp + ic * DD + 4);
                acc0.x += inv * w0.x;  acc0.y += inv * w0.y;
                acc0.z += inv * w0.z;  acc0.w += inv * w0.w;
                acc1.x += inv * w1v.x; acc1.y += inv * w1v.y;
                acc1.z += inv * w1v.z; acc1.w += inv * w1v.w;
            }
        }
    }
    float* op = out + (((size_t)(b << 14) + pix) << 5) + ocb;
    float4 r0 = {fmaxf(acc0.x, 0.f), fmaxf(acc0.y, 0.f), fmaxf(acc0.z, 0.f), fmaxf(acc0.w, 0.f)};
    float4 r1 = {fmaxf(acc1.x, 0.f), fmaxf(acc1.y, 0.f), fmaxf(acc1.z, 0.f), fmaxf(acc1.w, 0.f)};
    *(float4*)op = r0;
    *(float4*)(op + 4) = r1;
}

// ---------------- conv2: 3x3, 32->32, relu ----------------
__global__ __launch_bounds__(256) void conv2_kernel(
    const float* __restrict__ fin, const float* __restrict__ w2,
    const float* __restrict__ b2, float* __restrict__ out)
{
    __shared__ float wlds[9 * DD * DD];    // 36.9 KB
    int t = threadIdx.x;
    for (int idx = t; idx < 9 * DD * DD / 4; idx += 256)
        ((float4*)wlds)[idx] = ((const float4*)w2)[idx];
    __syncthreads();

    int ocq = t & 3;
    int pl  = t >> 2;
    int blk = blockIdx.x;                   // 512
    int b   = blk >> 8;
    int pix = (blk & 255) * 64 + pl;
    int i = pix >> 7, j = pix & 127;
    int ocb = ocq << 3;

    float4 acc0 = *(const float4*)(b2 + ocb);
    float4 acc1 = *(const float4*)(b2 + ocb + 4);
    #pragma unroll
    for (int dy = 0; dy < 3; dy++) {
        int ii = i + dy - 1;
        if (ii < 0 || ii >= HH) continue;
        #pragma unroll
        for (int dx = 0; dx < 3; dx++) {
            int jj = j + dx - 1;
            if (jj < 0 || jj >= WW) continue;
            const float* fr = fin + (((size_t)(b << 14) + ii * WW + jj)) * DD;
            float iv[DD];
            #pragma unroll
            for (int c = 0; c < DD / 4; c++)
                ((float4*)iv)[c] = *(const float4*)(fr + c * 4);
            const float* wp = wlds + (size_t)((dy * 3 + dx) * DD) * DD + ocb;
            #pragma unroll
            for (int ic = 0; ic < DD; ic++) {
                float inv = iv[ic];
                float4 w0 = *(const float4*)(wp + ic * DD);
                float4 w1v = *(const float4*)(wp + ic * DD + 4);
                acc0.x += inv * w0.x;  acc0.y += inv * w0.y;
                acc0.z += inv * w0.z;  acc0.w += inv * w0.w;
                acc1.x += inv * w1v.x; acc1.y += inv * w1v.y;
                acc1.z += inv * w1v.z; acc1.w += inv * w1v.w;
            }
        }
    }
    float* op = out + (((size_t)(b << 14) + pix) << 5) + ocb;
    float4 r0 = {fmaxf(acc0.x, 0.f), fmaxf(acc0.y, 0.f), fmaxf(acc0.z, 0.f), fmaxf(acc0.w, 0.f)};
    float4 r1 = {fmaxf(acc1.x, 0.f), fmaxf(acc1.y, 0.f), fmaxf(acc1.z, 0.f), fmaxf(acc1.w, 0.f)};
    *(float4*)op = r0;
    *(float4*)(op + 4) = r1;
}

// ---------------- k/q 1x1 projections + row norms ----------------
__global__ __launch_bounds__(256) void kq_kernel(
    const float* __restrict__ fin, const float* __restrict__ wk,
    const float* __restrict__ bk, const float* __restrict__ wq,
    float* __restrict__ ksb, float* __restrict__ qsb,
    float* __restrict__ knorm, float* __restrict__ qnorm)
{
    int g  = blockIdx.x * 256 + threadIdx.x;  // B*N*32
    int oc = g & 31;
    int bp = g >> 5;
    const float* fr = fin + (size_t)bp * DD;
    float ak = bk[oc], aq = 0.0f;
    #pragma unroll
    for (int ic = 0; ic < DD; ic += 4) {
        float4 fv = *(const float4*)(fr + ic);
        ak += fv.x * wk[(ic + 0) * DD + oc];
        ak += fv.y * wk[(ic + 1) * DD + oc];
        ak += fv.z * wk[(ic + 2) * DD + oc];
        ak += fv.w * wk[(ic + 3) * DD + oc];
        aq += fv.x * wq[(ic + 0) * DD + oc];
        aq += fv.y * wq[(ic + 1) * DD + oc];
        aq += fv.z * wq[(ic + 2) * DD + oc];
        aq += fv.w * wq[(ic + 3) * DD + oc];
    }
    ksb[g] = ak;
    qsb[g] = aq;
    float ssk = ak * ak, ssq = aq * aq;
    #pragma unroll
    for (int m = 1; m < 32; m <<= 1) {
        ssk += __shfl_xor(ssk, m, 64);
        ssq += __shfl_xor(ssq, m, 64);
    }
    if (oc == 0) {
        knorm[bp] = sqrtf(ssk);
        qnorm[bp] = sqrtf(ssq);
    }
}

// ---------------- edge scores: LDS-tiled exp(cosine) -> fp16 wT ----------
__global__ __launch_bounds__(256) void edge_kernel(
    const float* __restrict__ ksb, const float* __restrict__ qsb,
    const float* __restrict__ knorm, const float* __restrict__ qnorm,
    __half* __restrict__ wT, float* __restrict__ sums)
{
    __shared__ float kt[144][36];
    __shared__ float qt[64][36];
    __shared__ float kn[144];
    __shared__ float qn[64];
    __shared__ float red[4];
    const int t   = threadIdx.x;
    const int blk = blockIdx.x;     // 512
    const int b   = blk >> 8;
    const int tl  = blk & 255;
    const int ti0 = (tl >> 4) << 3, tj0 = (tl & 15) << 3;
    const float* kb = ksb + ((size_t)b << 19);
    const float* qb = qsb + ((size_t)b << 19);

    for (int idx = t; idx < 144 * 8; idx += 256) {
        int row = idx >> 3, quad = idx & 7;
        int ar = row / 12, ac = row - ar * 12;
        int gi = min(max(ti0 + ar - 2, 0), HH - 1);
        int gj = min(max(tj0 + ac - 2, 0), WW - 1);
        *(float4*)&kt[row][quad << 2] =
            *(const float4*)(kb + ((size_t)(gi * WW + gj) << 5) + (quad << 2));
    }
    for (int idx = t; idx < 64 * 8; idx += 256) {
        int row = idx >> 3, quad = idx & 7;
        int gp = (ti0 + (row >> 3)) * WW + tj0 + (row & 7);
        *(float4*)&qt[row][quad << 2] =
            *(const float4*)(qb + ((size_t)gp << 5) + (quad << 2));
    }
    if (t < 144) {
        int ar = t / 12, ac = t - ar * 12;
        int gi = min(max(ti0 + ar - 2, 0), HH - 1);
        int gj = min(max(tj0 + ac - 2, 0), WW - 1);
        kn[t] = knorm[(b << 14) + gi * WW + gj];
    } else if (t < 208) {
        int r2 = t - 144;
        int gp = (ti0 + (r2 >> 3)) * WW + tj0 + (r2 & 7);
        qn[r2] = qnorm[(b << 14) + gp];
    }
    __syncthreads();

    const int nl = t >> 2, s = t & 3;
    const int p = nl >> 3, q = nl & 7;
    float4 qv[8];
    #pragma unroll
    for (int c = 0; c < 8; c++) qv[c] = *(const float4*)&qt[nl][c << 2];
    const float qnv = qn[nl];
    const int gp = (ti0 + p) * WW + tj0 + q;
    __half* wrow = wT + (((size_t)(b << 14) + gp) << 5);
    float lsum = 0.0f;
    for (int o = s; o < 25; o += 4) {
        int di = o / 5, dj = o - di * 5;
        int krow = (p + di) * 12 + (q + dj);
        const float* kr = &kt[krow][0];
        float dot = 0.0f;
        #pragma unroll
        for (int c = 0; c < 8; c++) {
            float4 kv = *(const float4*)(kr + (c << 2));
            dot += qv[c].x * kv.x + qv[c].y * kv.y + qv[c].z * kv.z + qv[c].w * kv.w;
        }
        float den = fmaxf(qnv * kn[krow], EPSF);
        float es = expf(dot / den);     // cosine in [-1,1]: es in [0.37, 2.72]
        wrow[o] = __float2half(es);
        lsum += es;
    }
    #pragma unroll
    for (int mm = 1; mm < 64; mm <<= 1) lsum += __shfl_xor(lsum, mm, 64);
    if ((t & 63) == 0) red[t >> 6] = lsum;
    __syncthreads();
    if (t == 0) atomicAdd(&sums[b], red[0] + red[1] + red[2] + red[3]);
}

// ---------------- one propagation iteration ------------------------------
// Round-3 b128 LDS structure (full-rate: 8 lanes per 4-bank group, even
// spread) + fp16 GLOBAL h storage (validated: absmax unchanged). LDS holds
// fp32 float4 tiles (stride 17), converted once at stage time. DS-pipe work
// per thread-slab: 40 b128 reads + ~9 b128 writes (vs 196 b32 in round 6).
template<bool FIRST>
__global__ __launch_bounds__(256) void prop_it(
    const void* __restrict__ hsrc_, __half* __restrict__ hdst,
    const __half* __restrict__ wTh, const float* __restrict__ sums)
{
    __shared__ float4 tile_s[144 * 17];   // 39.2 KB
    __shared__ float wts_l[64 * 33];      // 8.4 KB
    const int t = threadIdx.x;
    const int x = blockIdx.x & 7;         // XCD slab swizzle
    const int r = blockIdx.x >> 3;
    const int g_tr = (x << 2) + (r >> 4); // global tile-row 0..31
    const int b   = g_tr >> 4;
    const int ti0 = (g_tr & 15) << 3;
    const int tj0 = (r & 15) << 3;

    // ---- stage wts (softmax-scaled, half -> float) ----
    {
        float invs = 1.0f / sums[b];
        int node = t >> 2, chunk = t & 3;        // 8 halfs per thread
        int p = node >> 3, q = node & 7;
        int gp = (ti0 + p) * WW + tj0 + q;
        const __half* wrow = wTh + (((size_t)(b << 14) + gp) << 5) + (chunk << 3);
        uint4 raw = *(const uint4*)wrow;
        const __half2* hp = (const __half2*)&raw;
        int base = node * 33 + (chunk << 3);
        #pragma unroll
        for (int u = 0; u < 4; u++) {
            float2 f = __half22float2(hp[u]);
            wts_l[base + 2 * u]     = f.x * invs;
            wts_l[base + 2 * u + 1] = f.y * invs;
        }
    }

    const int s  = t & 15;
    const int g  = t >> 4;
    const int q  = g & 7;
    const int rb = g >> 3;

    float4 acc[2][4];
    #pragma unroll
    for (int sl = 0; sl < 2; sl++)
        #pragma unroll
        for (int k = 0; k < 4; k++) acc[sl][k] = {0.f, 0.f, 0.f, 0.f};

    #pragma unroll
    for (int sl = 0; sl < 2; sl++) {
        __syncthreads();            // WAR on tile_s (and wts visibility @sl=0)
        if (FIRST) {
            // fp32 source: 2304 float4 tasks, 9 per thread
            #pragma unroll
            for (int j = 0; j < 9; j++) {
                int idx = (j << 8) + t;
                int pr = idx >> 4, slot = idx & 15;
                int ar = pr / 12, ac = pr - ar * 12;
                int gi = min(max(ti0 + ar - 2, 0), HH - 1);
                int gj = min(max(tj0 + ac - 2, 0), WW - 1);
                tile_s[pr * 17 + slot] = *(const float4*)((const float*)hsrc_ +
                    (((size_t)(b << 14) + gi * WW + gj) << 7) + (sl << 6) + (slot << 2));
            }
        } else {
            // fp16 source: 1152 tasks of 8 halfs -> two float4 slots
            #pragma unroll
            for (int j = 0; j < 5; j++) {
                int idx = (j << 8) + t;
                if (idx < 1152) {
                    int pr = idx >> 3, ck = idx & 7;
                    int ar = pr / 12, ac = pr - ar * 12;
                    int gi = min(max(ti0 + ar - 2, 0), HH - 1);
                    int gj = min(max(tj0 + ac - 2, 0), WW - 1);
                    const __half* src = (const __half*)hsrc_ +
                        (((size_t)(b << 14) + gi * WW + gj) << 7) + (sl << 6) + (ck << 3);
                    uint4 raw = *(const uint4*)src;
                    const __half2* hp = (const __half2*)&raw;
                    float2 f0 = __half22float2(hp[0]);
                    float2 f1 = __half22float2(hp[1]);
                    float2 f2 = __half22float2(hp[2]);
                    float2 f3 = __half22float2(hp[3]);
                    float4 lo = {f0.x, f0.y, f1.x, f1.y};
                    float4 hi = {f2.x, f2.y, f3.x, f3.y};
                    tile_s[pr * 17 + (ck << 1)]     = lo;
                    tile_s[pr * 17 + (ck << 1) + 1] = hi;
                }
            }
        }
        __syncthreads();

        // compute: register-blocked 4 nodes (k) per thread, b128 reads
        #pragma unroll
        for (int dj = 0; dj < 5; dj++) {
            int ccol = q + dj;
            #pragma unroll
            for (int a = 0; a < 8; a++) {
                int trow = (rb << 2) + a;
                float4 v = tile_s[(trow * 12 + ccol) * 17 + s];
                #pragma unroll
                for (int k = 0; k < 4; k++) {
                    if (k < a - 4 || k > a) continue;   // compile-time pruned
                    float w = wts_l[((((rb << 2) + k) << 3) + q) * 33 + (a - k) * 5 + dj];
                    acc[sl][k].x += w * v.x;
                    acc[sl][k].y += w * v.y;
                    acc[sl][k].z += w * v.z;
                    acc[sl][k].w += w * v.w;
                }
            }
        }
    }

    // ---- norm (shuffle over 16 s-lanes) + fp16 write ----
    #pragma unroll
    for (int k = 0; k < 4; k++) {
        float ss = acc[0][k].x * acc[0][k].x + acc[0][k].y * acc[0][k].y +
                   acc[0][k].z * acc[0][k].z + acc[0][k].w * acc[0][k].w +
                   acc[1][k].x * acc[1][k].x + acc[1][k].y * acc[1][k].y +
                   acc[1][k].z * acc[1][k].z + acc[1][k].w * acc[1][k].w;
        ss += __shfl_xor(ss, 1, 64);
        ss += __shfl_xor(ss, 2, 64);
        ss += __shfl_xor(ss, 4, 64);
        ss += __shfl_xor(ss, 8, 64);
        float rs = 1.0f / (sqrtf(ss) + EPSF);
        int gp = (ti0 + (rb << 2) + k) * WW + (tj0 + q);
        __half* orow = hdst + (((size_t)(b << 14) + gp) << 7);
        #pragma unroll
        for (int sl = 0; sl < 2; sl++) {
            union { uint2 u; __half2 h[2]; } pk;
            pk.h[0] = __floats2half2_rn(acc[sl][k].x * rs, acc[sl][k].y * rs);
            pk.h[1] = __floats2half2_rn(acc[sl][k].z * rs, acc[sl][k].w * rs);
            *(uint2*)(orow + (sl << 6) + (s << 2)) = pk.u;
        }
    }
}

// ---------------- mask head: fp16 h @ w_mask, softmax(16), transpose -----
__global__ __launch_bounds__(256) void mask_kernel(
    const __half* __restrict__ h, const float* __restrict__ wm,
    float* __restrict__ out)
{
    __shared__ float wls[QQ * MM];      // 8 KB, [c][m]
    __shared__ float part[64][4][20];
    const int t = threadIdx.x;
    for (int idx = t; idx < QQ * MM / 4; idx += 256)
        ((float4*)wls)[idx] = ((const float4*)wm)[idx];
    const int blk = blockIdx.x;         // 512
    const int b   = blk >> 8;
    const int n0  = (blk & 255) << 6;
    const int px  = t >> 2, s = t & 3;  // slot s: ch 32s..32s+31
    const __half* hr = h + ((((size_t)(b << 14) + n0 + px)) << 7) + (s << 5);
    __syncthreads();

    float acc[MM];
    #pragma unroll
    for (int m = 0; m < MM; m++) acc[m] = 0.0f;
    #pragma unroll
    for (int chunk = 0; chunk < 4; chunk++) {
        uint4 raw = ((const uint4*)hr)[chunk];
        const __half2* hp = (const __half2*)&raw;
        #pragma unroll
        for (int u = 0; u < 4; u++) {
            float2 hv = __half22float2(hp[u]);
            int c = (s << 5) + (chunk << 3) + 2 * u;
            const float* w0 = wls + (size_t)c * MM;
            const float* w1 = w0 + MM;
            #pragma unroll
            for (int m = 0; m < MM; m++)
                acc[m] += hv.x * w0[m] + hv.y * w1[m];
        }
    }
    #pragma unroll
    for (int m = 0; m < MM; m += 4)
        *(float4*)&part[px][s][m] = *(float4*)&acc[m];
    __syncthreads();

    float4 r = {0, 0, 0, 0};
    #pragma unroll
    for (int ss = 0; ss < 4; ss++) {
        float4 v = *(const float4*)&part[px][ss][s << 2];
        r.x += v.x; r.y += v.y; r.z += v.z; r.w += v.w;
    }
    float mx = fmaxf(fmaxf(r.x, r.y), fmaxf(r.z, r.w));
    mx = fmaxf(mx, __shfl_xor(mx, 1, 64));
    mx = fmaxf(mx, __shfl_xor(mx, 2, 64));
    float4 e = {expf(r.x - mx), expf(r.y - mx), expf(r.z - mx), expf(r.w - mx)};
    float ls = e.x + e.y + e.z + e.w;
    ls += __shfl_xor(ls, 1, 64);
    ls += __shfl_xor(ls, 2, 64);
    float inv = 1.0f / ls;
    float* ob = out + (((size_t)((b << 4) + (s << 2))) << 14) + n0 + px;
    ob[0]             = e.x * inv;
    ob[1 << 14]       = e.y * inv;
    ob[2 << 14]       = e.z * inv;
    ob[3 * (1 << 14)] = e.w * inv;
}

extern "C" void kernel_launch(void* const* d_in, const int* in_sizes, int n_in,
                              void* d_out, int out_size, void* d_ws, size_t ws_size,
                              hipStream_t stream)
{
    const float* x     = (const float*)d_in[0];
    // d_in[1] = edges (int32) -- unused: row/col are analytic
    const float* w1    = (const float*)d_in[2];
    const float* b1    = (const float*)d_in[3];
    const float* w2    = (const float*)d_in[4];
    const float* b2    = (const float*)d_in[5];
    const float* wk    = (const float*)d_in[6];
    const float* bk    = (const float*)d_in[7];
    const float* wq    = (const float*)d_in[8];
    const float* hinit = (const float*)d_in[9];
    const float* wm    = (const float*)d_in[10];
    float* out = (float*)d_out;

    char* ws = (char*)d_ws;
    size_t off = 0;
    auto alloc = [&](size_t bytes) -> void* {
        void* p = ws + off;
        off += (bytes + 255) & ~(size_t)255;
        return p;
    };
    float*  feat1 = (float*)alloc((size_t)NBATCH * NPIX * DD * 4);
    float*  feat2 = (float*)alloc((size_t)NBATCH * NPIX * DD * 4);
    float*  ksb   = (float*)alloc((size_t)NBATCH * NPIX * DD * 4);
    float*  qsb   = (float*)alloc((size_t)NBATCH * NPIX * DD * 4);
    float*  knorm = (float*)alloc((size_t)NBATCH * NPIX * 4);
    float*  qnorm = (float*)alloc((size_t)NBATCH * NPIX * 4);
    __half* wTh   = (__half*)alloc((size_t)NBATCH * NPIX * 32 * 2);
    float*  sums  = (float*)alloc(256);
    __half* hA    = (__half*)alloc((size_t)NBATCH * NPIX * QQ * 2);
    __half* hB    = (__half*)alloc((size_t)NBATCH * NPIX * QQ * 2);

    hipMemsetAsync(sums, 0, 2 * sizeof(float), stream);

    conv1_kernel<<<512, 256, 0, stream>>>(x, w1, b1, feat1);
    conv2_kernel<<<512, 256, 0, stream>>>(feat1, w2, b2, feat2);
    kq_kernel<<<4096, 256, 0, stream>>>(feat2, wk, bk, wq, ksb, qsb, knorm, qnorm);
    edge_kernel<<<512, 256, 0, stream>>>(ksb, qsb, knorm, qnorm, wTh, sums);

    prop_it<true><<<512, 256, 0, stream>>>((const void*)hinit, hA, wTh, sums);
    const __half* src = hA;
    __half* dst;
    for (int it = 1; it < 32; it++) {
        dst = (it & 1) ? hB : hA;
        prop_it<false><<<512, 256, 0, stream>>>((const void*)src, dst, wTh, sums);
        src = dst;
    }
    mask_kernel<<<512, 256, 0, stream>>>(src, wm, out);
}

// Round 8
// 626.866 us; speedup vs baseline: 10.1949x; 1.1127x over previous
//
#include <hip/hip_runtime.h>
#include <hip/hip_fp16.h>
#include <math.h>

#define HH 128
#define WW 128
#define NPIX 16384
#define CIN 3
#define DD 32
#define QQ 128
#define MM 16
#define NBATCH 2
#define EPSF 1e-8f

// ---------------- conv1: 3x3, 3->32, relu, zero-pad SAME ----------------
__global__ __launch_bounds__(256) void conv1_kernel(
    const float* __restrict__ x, const float* __restrict__ w1,
    const float* __restrict__ b1, float* __restrict__ out)
{
    __shared__ float wlds[9 * CIN * DD];
    int t = threadIdx.x;
    for (int idx = t; idx < 9 * CIN * DD / 4; idx += 256)
        ((float4*)wlds)[idx] = ((const float4*)w1)[idx];
    __syncthreads();

    int ocq = t & 3;
    int pl  = t >> 2;
    int blk = blockIdx.x;                   // 512
    int b   = blk >> 8;
    int pix = (blk & 255) * 64 + pl;
    int i = pix >> 7, j = pix & 127;
    int ocb = ocq << 3;

    float4 acc0 = *(const float4*)(b1 + ocb);
    float4 acc1 = *(const float4*)(b1 + ocb + 4);
    #pragma unroll
    for (int dy = 0; dy < 3; dy++) {
        int ii = i + dy - 1;
        if (ii < 0 || ii >= HH) continue;
        #pragma unroll
        for (int dx = 0; dx < 3; dx++) {
            int jj = j + dx - 1;
            if (jj < 0 || jj >= WW) continue;
            const float* fr = x + ((size_t)((b << 14) + ii * WW + jj)) * CIN;
            float in0 = fr[0], in1 = fr[1], in2 = fr[2];
            const float* wp = wlds + (size_t)((dy * 3 + dx) * CIN) * DD + ocb;
            #pragma unroll
            for (int ic = 0; ic < 3; ic++) {
                float inv = (ic == 0) ? in0 : (ic == 1) ? in1 : in2;
                float4 w0 = *(const float4*)(wp + ic * DD);
                float4 w1v = *(const float4*)(wp + ic * DD + 4);
                acc0.x += inv * w0.x;  acc0.y += inv * w0.y;
                acc0.z += inv * w0.z;  acc0.w += inv * w0.w;
                acc1.x += inv * w1v.x; acc1.y += inv * w1v.y;
                acc1.z += inv * w1v.z; acc1.w += inv * w1v.w;
            }
        }
    }
    float* op = out + (((size_t)(b << 14) + pix) << 5) + ocb;
    float4 r0 = {fmaxf(acc0.x, 0.f), fmaxf(acc0.y, 0.f), fmaxf(acc0.z, 0.f), fmaxf(acc0.w, 0.f)};
    float4 r1 = {fmaxf(acc1.x, 0.f), fmaxf(acc1.y, 0.f), fmaxf(acc1.z, 0.f), fmaxf(acc1.w, 0.f)};
    *(float4*)op = r0;
    *(float4*)(op + 4) = r1;
}

// ---------------- conv2: 3x3, 32->32, relu ----------------
__global__ __launch_bounds__(256) void conv2_kernel(
    const float* __restrict__ fin, const float* __restrict__ w2,
    const float* __restrict__ b2, float* __restrict__ out)
{
    __shared__ float wlds[9 * DD * DD];    // 36.9 KB
    int t = threadIdx.x;
    for (int idx = t; idx < 9 * DD * DD / 4; idx += 256)
        ((float4*)wlds)[idx] = ((const float4*)w2)[idx];
    __syncthreads();

    int ocq = t & 3;
    int pl  = t >> 2;
    int blk = blockIdx.x;                   // 512
    int b   = blk >> 8;
    int pix = (blk & 255) * 64 + pl;
    int i = pix >> 7, j = pix & 127;
    int ocb = ocq << 3;

    float4 acc0 = *(const float4*)(b2 + ocb);
    float4 acc1 = *(const float4*)(b2 + ocb + 4);
    #pragma unroll
    for (int dy = 0; dy < 3; dy++) {
        int ii = i + dy - 1;
        if (ii < 0 || ii >= HH) continue;
        #pragma unroll
        for (int dx = 0; dx < 3; dx++) {
            int jj = j + dx - 1;
            if (jj < 0 || jj >= WW) continue;
            const float* fr = fin + (((size_t)(b << 14) + ii * WW + jj)) * DD;
            float iv[DD];
            #pragma unroll
            for (int c = 0; c < DD / 4; c++)
                ((float4*)iv)[c] = *(const float4*)(fr + c * 4);
            const float* wp = wlds + (size_t)((dy * 3 + dx) * DD) * DD + ocb;
            #pragma unroll
            for (int ic = 0; ic < DD; ic++) {
                float inv = iv[ic];
                float4 w0 = *(const float4*)(wp + ic * DD);
                float4 w1v = *(const float4*)(wp + ic * DD + 4);
                acc0.x += inv * w0.x;  acc0.y += inv * w0.y;
                acc0.z += inv * w0.z;  acc0.w += inv * w0.w;
                acc1.x += inv * w1v.x; acc1.y += inv * w1v.y;
                acc1.z += inv * w1v.z; acc1.w += inv * w1v.w;
            }
        }
    }
    float* op = out + (((size_t)(b << 14) + pix) << 5) + ocb;
    float4 r0 = {fmaxf(acc0.x, 0.f), fmaxf(acc0.y, 0.f), fmaxf(acc0.z, 0.f), fmaxf(acc0.w, 0.f)};
    float4 r1 = {fmaxf(acc1.x, 0.f), fmaxf(acc1.y, 0.f), fmaxf(acc1.z, 0.f), fmaxf(acc1.w, 0.f)};
    *(float4*)op = r0;
    *(float4*)(op + 4) = r1;
}

// ---------------- k/q 1x1 projections + row norms ----------------
__global__ __launch_bounds__(256) void kq_kernel(
    const float* __restrict__ fin, const float* __restrict__ wk,
    const float* __restrict__ bk, const float* __restrict__ wq,
    float* __restrict__ ksb, float* __restrict__ qsb,
    float* __restrict__ knorm, float* __restrict__ qnorm)
{
    int g  = blockIdx.x * 256 + threadIdx.x;  // B*N*32
    int oc = g & 31;
    int bp = g >> 5;
    const float* fr = fin + (size_t)bp * DD;
    float ak = bk[oc], aq = 0.0f;
    #pragma unroll
    for (int ic = 0; ic < DD; ic += 4) {
        float4 fv = *(const float4*)(fr + ic);
        ak += fv.x * wk[(ic + 0) * DD + oc];
        ak += fv.y * wk[(ic + 1) * DD + oc];
        ak += fv.z * wk[(ic + 2) * DD + oc];
        ak += fv.w * wk[(ic + 3) * DD + oc];
        aq += fv.x * wq[(ic + 0) * DD + oc];
        aq += fv.y * wq[(ic + 1) * DD + oc];
        aq += fv.z * wq[(ic + 2) * DD + oc];
        aq += fv.w * wq[(ic + 3) * DD + oc];
    }
    ksb[g] = ak;
    qsb[g] = aq;
    float ssk = ak * ak, ssq = aq * aq;
    #pragma unroll
    for (int m = 1; m < 32; m <<= 1) {
        ssk += __shfl_xor(ssk, m, 64);
        ssq += __shfl_xor(ssq, m, 64);
    }
    if (oc == 0) {
        knorm[bp] = sqrtf(ssk);
        qnorm[bp] = sqrtf(ssq);
    }
}

// ---------------- edge scores: LDS-tiled exp(cosine) -> fp16 wT ----------
__global__ __launch_bounds__(256) void edge_kernel(
    const float* __restrict__ ksb, const float* __restrict__ qsb,
    const float* __restrict__ knorm, const float* __restrict__ qnorm,
    __half* __restrict__ wT, float* __restrict__ sums)
{
    __shared__ float kt[144][36];
    __shared__ float qt[64][36];
    __shared__ float kn[144];
    __shared__ float qn[64];
    __shared__ float red[4];
    const int t   = threadIdx.x;
    const int blk = blockIdx.x;     // 512
    const int b   = blk >> 8;
    const int tl  = blk & 255;
    const int ti0 = (tl >> 4) << 3, tj0 = (tl & 15) << 3;
    const float* kb = ksb + ((size_t)b << 19);
    const float* qb = qsb + ((size_t)b << 19);

    for (int idx = t; idx < 144 * 8; idx += 256) {
        int row = idx >> 3, quad = idx & 7;
        int ar = row / 12, ac = row - ar * 12;
        int gi = min(max(ti0 + ar - 2, 0), HH - 1);
        int gj = min(max(tj0 + ac - 2, 0), WW - 1);
        *(float4*)&kt[row][quad << 2] =
            *(const float4*)(kb + ((size_t)(gi * WW + gj) << 5) + (quad << 2));
    }
    for (int idx = t; idx < 64 * 8; idx += 256) {
        int row = idx >> 3, quad = idx & 7;
        int gp = (ti0 + (row >> 3)) * WW + tj0 + (row & 7);
        *(float4*)&qt[row][quad << 2] =
            *(const float4*)(qb + ((size_t)gp << 5) + (quad << 2));
    }
    if (t < 144) {
        int ar = t / 12, ac = t - ar * 12;
        int gi = min(max(ti0 + ar - 2, 0), HH - 1);
        int gj = min(max(tj0 + ac - 2, 0), WW - 1);
        kn[t] = knorm[(b << 14) + gi * WW + gj];
    } else if (t < 208) {
        int r2 = t - 144;
        int gp = (ti0 + (r2 >> 3)) * WW + tj0 + (r2 & 7);
        qn[r2] = qnorm[(b << 14) + gp];
    }
    __syncthreads();

    const int nl = t >> 2, s = t & 3;
    const int p = nl >> 3, q = nl & 7;
    float4 qv[8];
    #pragma unroll
    for (int c = 0; c < 8; c++) qv[c] = *(const float4*)&qt[nl][c << 2];
    const float qnv = qn[nl];
    const int gp = (ti0 + p) * WW + tj0 + q;
    __half* wrow = wT + (((size_t)(b << 14) + gp) << 5);
    float lsum = 0.0f;
    for (int o = s; o < 25; o += 4) {
        int di = o / 5, dj = o - di * 5;
        int krow = (p + di) * 12 + (q + dj);
        const float* kr = &kt[krow][0];
        float dot = 0.0f;
        #pragma unroll
        for (int c = 0; c < 8; c++) {
            float4 kv = *(const float4*)(kr + (c << 2));
            dot += qv[c].x * kv.x + qv[c].y * kv.y + qv[c].z * kv.z + qv[c].w * kv.w;
        }
        float den = fmaxf(qnv * kn[krow], EPSF);
        float es = expf(dot / den);     // cosine in [-1,1]: es in [0.37, 2.72]
        wrow[o] = __float2half(es);
        lsum += es;
    }
    #pragma unroll
    for (int mm = 1; mm < 64; mm <<= 1) lsum += __shfl_xor(lsum, mm, 64);
    if ((t & 63) == 0) red[t >> 6] = lsum;
    __syncthreads();
    if (t == 0) atomicAdd(&sums[b], red[0] + red[1] + red[2] + red[3]);
}

// ---------------- one propagation iteration ------------------------------
// R3's full-rate DS pattern (task = one float4 slot, slot=idx&15, ONE
// ds_write_b128) with fp16 global h: load uint2 (4 halfs), 2 pk-cvts, one
// write. LAST variant fuses the mask head from the normalized registers
// (R5-validated epilogue) and skips the final h write + mask launch.
template<bool FIRST, bool LAST>
__global__ __launch_bounds__(256) void prop_it(
    const void* __restrict__ hsrc_, __half* __restrict__ hdst,
    const __half* __restrict__ wTh, const float* __restrict__ sums,
    const float* __restrict__ wm, float* __restrict__ out)
{
    __shared__ float4 tile_s[144 * 17];   // 39.2 KB
    __shared__ float wts_l[2176];         // 8.7 KB (stride-17 capable)
    const int t = threadIdx.x;
    const int x = blockIdx.x & 7;         // XCD slab swizzle
    const int r = blockIdx.x >> 3;
    const int g_tr = (x << 2) + (r >> 4); // global tile-row 0..31
    const int b   = g_tr >> 4;
    const int ti0 = (g_tr & 15) << 3;
    const int tj0 = (r & 15) << 3;

    // ---- stage wts (softmax-scaled, half -> float), stride 33 ----
    {
        float invs = 1.0f / sums[b];
        int node = t >> 2, chunk = t & 3;        // 8 halfs per thread
        int p = node >> 3, q = node & 7;
        int gp = (ti0 + p) * WW + tj0 + q;
        const __half* wrow = wTh + (((size_t)(b << 14) + gp) << 5) + (chunk << 3);
        uint4 raw = *(const uint4*)wrow;
        const __half2* hp = (const __half2*)&raw;
        int base = node * 33 + (chunk << 3);
        #pragma unroll
        for (int u = 0; u < 4; u++) {
            float2 f = __half22float2(hp[u]);
            wts_l[base + 2 * u]     = f.x * invs;
            wts_l[base + 2 * u + 1] = f.y * invs;
        }
    }

    const int s  = t & 15;
    const int g  = t >> 4;
    const int q  = g & 7;
    const int rb = g >> 3;

    float4 acc[2][4];
    #pragma unroll
    for (int sl = 0; sl < 2; sl++)
        #pragma unroll
        for (int k = 0; k < 4; k++) acc[sl][k] = {0.f, 0.f, 0.f, 0.f};

    #pragma unroll
    for (int sl = 0; sl < 2; sl++) {
        __syncthreads();            // WAR on tile_s (and wts visibility @sl=0)
        // 2304 tasks (144 px x 16 slots), 9 per thread, ONE b128 write each
        #pragma unroll
        for (int j = 0; j < 9; j++) {
            int idx = (j << 8) + t;
            int pr = idx >> 4, slot = idx & 15;
            int ar = pr / 12, ac = pr - ar * 12;
            int gi = min(max(ti0 + ar - 2, 0), HH - 1);
            int gj = min(max(tj0 + ac - 2, 0), WW - 1);
            if (FIRST) {
                tile_s[pr * 17 + slot] = *(const float4*)((const float*)hsrc_ +
                    (((size_t)(b << 14) + gi * WW + gj) << 7) + (sl << 6) + (slot << 2));
            } else {
                const __half* src = (const __half*)hsrc_ +
                    (((size_t)(b << 14) + gi * WW + gj) << 7) + (sl << 6) + (slot << 2);
                uint2 raw = *(const uint2*)src;       // 4 halfs
                const __half2* hp = (const __half2*)&raw;
                float2 f0 = __half22float2(hp[0]);
                float2 f1 = __half22float2(hp[1]);
                float4 v = {f0.x, f0.y, f1.x, f1.y};
                tile_s[pr * 17 + slot] = v;
            }
        }
        __syncthreads();

        // compute: register-blocked 4 nodes (k) per thread, b128 reads
        #pragma unroll
        for (int dj = 0; dj < 5; dj++) {
            int ccol = q + dj;
            #pragma unroll
            for (int a = 0; a < 8; a++) {
                int trow = (rb << 2) + a;
                float4 v = tile_s[(trow * 12 + ccol) * 17 + s];
                #pragma unroll
                for (int k = 0; k < 4; k++) {
                    if (k < a - 4 || k > a) continue;   // compile-time pruned
                    float w = wts_l[((((rb << 2) + k) << 3) + q) * 33 + (a - k) * 5 + dj];
                    acc[sl][k].x += w * v.x;
                    acc[sl][k].y += w * v.y;
                    acc[sl][k].z += w * v.z;
                    acc[sl][k].w += w * v.w;
                }
            }
        }
    }

    // ---- norm (shuffle over 16 s-lanes); write fp16 h unless LAST ----
    #pragma unroll
    for (int k = 0; k < 4; k++) {
        float ss = acc[0][k].x * acc[0][k].x + acc[0][k].y * acc[0][k].y +
                   acc[0][k].z * acc[0][k].z + acc[0][k].w * acc[0][k].w +
                   acc[1][k].x * acc[1][k].x + acc[1][k].y * acc[1][k].y +
                   acc[1][k].z * acc[1][k].z + acc[1][k].w * acc[1][k].w;
        ss += __shfl_xor(ss, 1, 64);
        ss += __shfl_xor(ss, 2, 64);
        ss += __shfl_xor(ss, 4, 64);
        ss += __shfl_xor(ss, 8, 64);
        float rs = 1.0f / (sqrtf(ss) + EPSF);
        #pragma unroll
        for (int sl = 0; sl < 2; sl++) {
            acc[sl][k].x *= rs; acc[sl][k].y *= rs;
            acc[sl][k].z *= rs; acc[sl][k].w *= rs;
        }
        if (!LAST) {
            int gp = (ti0 + (rb << 2) + k) * WW + (tj0 + q);
            __half* orow = hdst + (((size_t)(b << 14) + gp) << 7);
            #pragma unroll
            for (int sl = 0; sl < 2; sl++) {
                union { uint2 u; __half2 h[2]; } pk;
                pk.h[0] = __floats2half2_rn(acc[sl][k].x, acc[sl][k].y);
                pk.h[1] = __floats2half2_rn(acc[sl][k].z, acc[sl][k].w);
                *(uint2*)(orow + (sl << 6) + (s << 2)) = pk.u;
            }
        }
    }

    if (LAST) {
        // ---- fused mask head (R5-validated): logits from registers ----
        __syncthreads();                 // tile_s / wts_l reads all done
        for (int idx = t; idx < QQ * MM; idx += 256) {
            int c = idx >> 4, m = idx & 15;
            wts_l[c * 17 + m] = wm[idx]; // stride 17: conflict-free row reads
        }
        __syncthreads();

        float pm[4][16];
        #pragma unroll
        for (int k = 0; k < 4; k++)
            #pragma unroll
            for (int m = 0; m < 16; m++) pm[k][m] = 0.0f;
        #pragma unroll
        for (int k = 0; k < 4; k++) {
            #pragma unroll
            for (int j = 0; j < 4; j++) {
                float h0 = ((const float*)&acc[0][k])[j];   // ch 4s+j
                float h1 = ((const float*)&acc[1][k])[j];   // ch 64+4s+j
                const float* w0 = wts_l + ((4 * s + j) * 17);
                const float* w1 = wts_l + ((64 + 4 * s + j) * 17);
                #pragma unroll
                for (int m = 0; m < 16; m++)
                    pm[k][m] += h0 * w0[m] + h1 * w1[m];
            }
        }
        #pragma unroll
        for (int k = 0; k < 4; k++)
            #pragma unroll
            for (int m = 0; m < 16; m++) {
                pm[k][m] += __shfl_xor(pm[k][m], 1, 64);
                pm[k][m] += __shfl_xor(pm[k][m], 2, 64);
                pm[k][m] += __shfl_xor(pm[k][m], 4, 64);
                pm[k][m] += __shfl_xor(pm[k][m], 8, 64);
            }
        __syncthreads();
        float* maskbuf = (float*)tile_s;      // [64 px][17]
        #pragma unroll
        for (int k = 0; k < 4; k++) {
            float mx = pm[k][0];
            #pragma unroll
            for (int m = 1; m < 16; m++) mx = fmaxf(mx, pm[k][m]);
            float sum = 0.0f;
            float es[16];
            #pragma unroll
            for (int m = 0; m < 16; m++) { es[m] = expf(pm[k][m] - mx); sum += es[m]; }
            float inv = 1.0f / sum;
            float val = 0.0f;                 // select es[s] w/o dynamic index
            #pragma unroll
            for (int m = 0; m < 16; m++) if (m == s) val = es[m];
            int nl = (((rb << 2) + k) << 3) + q;
            maskbuf[nl * 17 + s] = val * inv;
        }
        __syncthreads();
        {
            int m = t >> 4, grp = t & 15;
            #pragma unroll
            for (int e = 0; e < 4; e++) {
                int px = (grp << 2) + e;
                int p = px >> 3, qq = px & 7;
                out[(((size_t)((b << 4) + m)) << 14) + (ti0 + p) * WW + (tj0 + qq)] =
                    maskbuf[px * 17 + m];
            }
        }
    }
}

extern "C" void kernel_launch(void* const* d_in, const int* in_sizes, int n_in,
                              void* d_out, int out_size, void* d_ws, size_t ws_size,
                              hipStream_t stream)
{
    const float* x     = (const float*)d_in[0];
    // d_in[1] = edges (int32) -- unused: row/col are analytic
    const float* w1    = (const float*)d_in[2];
    const float* b1    = (const float*)d_in[3];
    const float* w2    = (const float*)d_in[4];
    const float* b2    = (const float*)d_in[5];
    const float* wk    = (const float*)d_in[6];
    const float* bk    = (const float*)d_in[7];
    const float* wq    = (const float*)d_in[8];
    const float* hinit = (const float*)d_in[9];
    const float* wm    = (const float*)d_in[10];
    float* out = (float*)d_out;

    char* ws = (char*)d_ws;
    size_t off = 0;
    auto alloc = [&](size_t bytes) -> void* {
        void* p = ws + off;
        off += (bytes + 255) & ~(size_t)255;
        return p;
    };
    float*  feat1 = (float*)alloc((size_t)NBATCH * NPIX * DD * 4);
    float*  feat2 = (float*)alloc((size_t)NBATCH * NPIX * DD * 4);
    float*  ksb   = (float*)alloc((size_t)NBATCH * NPIX * DD * 4);
    float*  qsb   = (float*)alloc((size_t)NBATCH * NPIX * DD * 4);
    float*  knorm = (float*)alloc((size_t)NBATCH * NPIX * 4);
    float*  qnorm = (float*)alloc((size_t)NBATCH * NPIX * 4);
    __half* wTh   = (__half*)alloc((size_t)NBATCH * NPIX * 32 * 2);
    float*  sums  = (float*)alloc(256);
    __half* hA    = (__half*)alloc((size_t)NBATCH * NPIX * QQ * 2);
    __half* hB    = (__half*)alloc((size_t)NBATCH * NPIX * QQ * 2);

    hipMemsetAsync(sums, 0, 2 * sizeof(float), stream);

    conv1_kernel<<<512, 256, 0, stream>>>(x, w1, b1, feat1);
    conv2_kernel<<<512, 256, 0, stream>>>(feat1, w2, b2, feat2);
    kq_kernel<<<4096, 256, 0, stream>>>(feat2, wk, bk, wq, ksb, qsb, knorm, qnorm);
    edge_kernel<<<512, 256, 0, stream>>>(ksb, qsb, knorm, qnorm, wTh, sums);

    prop_it<true, false><<<512, 256, 0, stream>>>((const void*)hinit, hA, wTh, sums, wm, out);
    const __half* src = hA;
    __half* dst;
    for (int it = 1; it < 31; it++) {
        dst = (it & 1) ? hB : hA;
        prop_it<false, false><<<512, 256, 0, stream>>>((const void*)src, dst, wTh, sums, wm, out);
        src = dst;
    }
    prop_it<false, true><<<512, 256, 0, stream>>>((const void*)src, nullptr, wTh, sums, wm, out);
}